// Round 11
// baseline (604.600 us; speedup 1.0000x reference)
//
#include <hip/hip_runtime.h>

typedef unsigned short u16;
typedef __attribute__((ext_vector_type(8))) short short8;
typedef __attribute__((ext_vector_type(4))) float float4v;

#define HID 64
#define MOLD 9
#define BSH 10           // bucket covers 1<<BSH = 1024 nodes
#define NBM 256          // max buckets (N <= 262144; src packs in 18 bits)
#define NBLK 256         // partition blocks

__device__ __forceinline__ float bf2f(u16 u) {
    return __uint_as_float(((unsigned)u) << 16);
}
__device__ __forceinline__ u16 f2bf(float f) {
    unsigned x = __float_as_uint(f);
    unsigned r = (x + 0x7FFFu + ((x >> 16) & 1u)) >> 16;  // round-nearest-even
    return (u16)r;
}
__device__ __forceinline__ void unpack_add(uint4 r, float* a) {
    a[0] += __uint_as_float(r.x << 16); a[1] += __uint_as_float(r.x & 0xffff0000u);
    a[2] += __uint_as_float(r.y << 16); a[3] += __uint_as_float(r.y & 0xffff0000u);
    a[4] += __uint_as_float(r.z << 16); a[5] += __uint_as_float(r.z & 0xffff0000u);
    a[6] += __uint_as_float(r.w << 16); a[7] += __uint_as_float(r.w & 0xffff0000u);
}
__device__ __forceinline__ void unpack_set(uint4 r, float* a) {
    a[0] = __uint_as_float(r.x << 16); a[1] = __uint_as_float(r.x & 0xffff0000u);
    a[2] = __uint_as_float(r.y << 16); a[3] = __uint_as_float(r.y & 0xffff0000u);
    a[4] = __uint_as_float(r.z << 16); a[5] = __uint_as_float(r.z & 0xffff0000u);
    a[6] = __uint_as_float(r.w << 16); a[7] = __uint_as_float(r.w & 0xffff0000u);
}
__device__ __forceinline__ void unpack_add2(uint2 r, float* a) {
    a[0] += __uint_as_float(r.x << 16); a[1] += __uint_as_float(r.x & 0xffff0000u);
    a[2] += __uint_as_float(r.y << 16); a[3] += __uint_as_float(r.y & 0xffff0000u);
}
__device__ __forceinline__ void unpack_set2(uint2 r, float* a) {
    a[0] = __uint_as_float(r.x << 16); a[1] = __uint_as_float(r.x & 0xffff0000u);
    a[2] = __uint_as_float(r.y << 16); a[3] = __uint_as_float(r.y & 0xffff0000u);
}

// ---- dtype probe (self-initializing; no pre-memset needed) ----
__global__ void k_detect(const u16* __restrict__ p, int n, int* __restrict__ flag) {
    __shared__ int bad;
    if (threadIdx.x == 0) bad = 0;
    __syncthreads();
    bool b = false;
    for (int i = threadIdx.x; i < n; i += 256) {
        float v = bf2f(p[i]);
        if (!(v == v) || fabsf(v) > 1000.f) b = true;
    }
    if (b) atomicOr(&bad, 1);
    __syncthreads();
    if (threadIdx.x == 0) *flag = bad;
}

// ---- stage weights as bf16 + zero pooling buffers (replaces 3 memsets) ----
__global__ void k_cvt_w(const void* W1, const void* b1, const void* W2, const void* b2,
                        const void* W3, const void* b3, const void* Wl, const void* bl,
                        const int* __restrict__ flag, u16* __restrict__ wbf,
                        float* __restrict__ hsum, int* __restrict__ hmax,
                        int* __restrict__ cnt, int G) {
    int mode = *flag;
    int gid = blockIdx.x * 256 + threadIdx.x;
    int gtot = gridDim.x * 256;
    if (gid < 17216) {
        int i = gid;
        const void* s; int base;
        if (i < 576)        { s = W1; base = 0; }
        else if (i < 640)   { s = b1; base = 576; }
        else if (i < 4736)  { s = W2; base = 640; }
        else if (i < 4800)  { s = b2; base = 4736; }
        else if (i < 8896)  { s = W3; base = 4800; }
        else if (i < 8960)  { s = b3; base = 8896; }
        else if (i < 17152) { s = Wl; base = 8960; }
        else                { s = bl; base = 17152; }
        int o = i - base;
        wbf[i] = mode ? f2bf(((const float*)s)[o]) : ((const u16*)s)[o];
    }
    for (int j = gid; j < G * HID; j += gtot) { hsum[j] = 0.f; hmax[j] = 0; }
    for (int j = gid; j < G; j += gtot) cnt[j] = 0;
}

// ==== atomic-free two-level radix CSR build ====
__global__ __launch_bounds__(256) void k_hist(const int* __restrict__ ei, int E, int nb,
                                              int chunk, int* __restrict__ cntmat) {
    __shared__ int h[NBM];
    int tid = threadIdx.x, k = blockIdx.x;
    for (int i = tid; i < nb; i += 256) h[i] = 0;
    __syncthreads();
    int e0 = k * chunk, e1 = e0 + chunk; if (e1 > E) e1 = E;
    for (int e = e0 + tid; e < e1; e += 256)
        atomicAdd(&h[ei[E + e] >> BSH], 1);
    __syncthreads();
    for (int b = tid; b < nb; b += 256) cntmat[b * NBLK + k] = h[b];
}

__global__ __launch_bounds__(1024) void k_scanmat(int* __restrict__ cntmat, int total) {
    __shared__ int ps[1024];
    int tid = threadIdx.x;
    int chunk = (total + 1023) >> 10;
    int i0 = tid * chunk, i1 = i0 + chunk; if (i1 > total) i1 = total;
    int sum = 0;
    for (int i = i0; i < i1; i++) sum += cntmat[i];
    ps[tid] = sum;
    __syncthreads();
    for (int off = 1; off < 1024; off <<= 1) {
        int t = (tid >= off) ? ps[tid - off] : 0;
        __syncthreads();
        ps[tid] += t;
        __syncthreads();
    }
    int run = ps[tid] - sum;
    for (int i = i0; i < i1; i++) { int c = cntmat[i]; cntmat[i] = run; run += c; }
}

__global__ __launch_bounds__(256) void k_scatter(const int* __restrict__ ei, int E, int nb,
                                                 int chunk, const int* __restrict__ offmat,
                                                 unsigned* __restrict__ staging) {
    __shared__ int cur[NBM];
    int tid = threadIdx.x, k = blockIdx.x;
    for (int b = tid; b < nb; b += 256) cur[b] = offmat[b * NBLK + k];
    __syncthreads();
    int e0 = k * chunk, e1 = e0 + chunk; if (e1 > E) e1 = E;
    for (int e = e0 + tid; e < e1; e += 256) {
        int s = ei[e];
        int d = ei[E + e];
        int b = d >> BSH;
        int p = atomicAdd(&cur[b], 1);
        staging[p] = (unsigned)s | ((unsigned)(d & ((1 << BSH) - 1)) << 18);
    }
}

__global__ __launch_bounds__(256) void k_p4(const unsigned* __restrict__ staging,
                                            const int* __restrict__ offmat, int nb, int N, int E,
                                            int* __restrict__ col, int* __restrict__ rowptr,
                                            float* __restrict__ dinv) {
    __shared__ int cnt[1 << BSH];
    __shared__ int cur[1 << BSH];
    __shared__ int ps[256];
    int b = blockIdx.x, tid = threadIdx.x;
    int s0 = offmat[b * NBLK];
    int s1 = (b == nb - 1) ? E : offmat[(b + 1) * NBLK];
    for (int i = tid; i < (1 << BSH); i += 256) cnt[i] = 0;
    __syncthreads();
    for (int i = s0 + tid; i < s1; i += 256)
        atomicAdd(&cnt[staging[i] >> 18], 1);
    __syncthreads();
    int base4 = tid * 4;
    int c0 = cnt[base4], c1 = cnt[base4 + 1], c2 = cnt[base4 + 2], c3 = cnt[base4 + 3];
    int tsum = c0 + c1 + c2 + c3;
    ps[tid] = tsum;
    __syncthreads();
    for (int off = 1; off < 256; off <<= 1) {
        int t = (tid >= off) ? ps[tid - off] : 0;
        __syncthreads();
        ps[tid] += t;
        __syncthreads();
    }
    int ex = ps[tid] - tsum;
    int o0 = s0 + ex, o1 = o0 + c0, o2 = o1 + c1, o3 = o2 + c2;
    cur[base4] = o0; cur[base4 + 1] = o1; cur[base4 + 2] = o2; cur[base4 + 3] = o3;
    int v = (b << BSH) + base4;
    if (v < N)     { rowptr[v] = o0;     dinv[v] = rsqrtf((float)(c0 + 1)); }
    if (v + 1 < N) { rowptr[v + 1] = o1; dinv[v + 1] = rsqrtf((float)(c1 + 1)); }
    if (v + 2 < N) { rowptr[v + 2] = o2; dinv[v + 2] = rsqrtf((float)(c2 + 1)); }
    if (v + 3 < N) { rowptr[v + 3] = o3; dinv[v + 3] = rsqrtf((float)(c3 + 1)); }
    if (b == nb - 1 && tid == 0) rowptr[N] = E;
    __syncthreads();
    for (int i = s0 + tid; i < s1; i += 256) {
        unsigned w = staging[i];
        int p = atomicAdd(&cur[w >> 18], 1);
        col[p] = (int)(w & 0x3FFFF);
    }
}

// ---- stage x into two L2-resident tables: x8d[v][8] (16B rows) + x9d[v] (2B) ----
// both pre-scaled by dinv[v]
__global__ void k_cvt_x(const void* __restrict__ x, const float* __restrict__ dinv,
                        const int* __restrict__ flag, int N,
                        u16* __restrict__ x8d, u16* __restrict__ x9d) {
    int mode = *flag;
    int i = blockIdx.x * 256 + threadIdx.x;
    if (i >= N * 9) return;
    if (i < N * 8) {
        int v = i >> 3, f = i & 7;
        float val = mode ? ((const float*)x)[v * MOLD + f]
                         : bf2f(((const u16*)x)[v * MOLD + f]);
        x8d[i] = f2bf(val * dinv[v]);
    } else {
        int v = i - N * 8;
        float val = mode ? ((const float*)x)[v * MOLD + 8]
                         : bf2f(((const u16*)x)[v * MOLD + 8]);
        x9d[v] = f2bf(val * dinv[v]);
    }
}

// ---- layer-1 gather over L2-resident x8/x9 tables, fused W1 ----
// lane: fp = lane&1 (4-feat half of 16B row), eslot = lane>>1 (32 edges/inst).
// fp==1 lanes also accumulate x9. h1[v][lane] written 128B-coalesced per node.
__global__ __launch_bounds__(256, 4) void k_aggx(
        const u16* __restrict__ x8d, const u16* __restrict__ x9d,
        const int* __restrict__ rowptr, const int* __restrict__ col,
        const float* __restrict__ dinv, const u16* __restrict__ W1,
        const u16* __restrict__ b1, int N, u16* __restrict__ h1) {
    int lane = threadIdx.x & 63;
    int fp = lane & 1, eslot = lane >> 1;
    float w1a[8];
#pragma unroll
    for (int k = 0; k < 8; k++) w1a[k] = bf2f(W1[k * HID + lane]);
    float w1b = bf2f(W1[8 * HID + lane]);
    float bias = bf2f(b1[lane]);
    bool bit1 = (lane & 2) != 0, bit2 = (lane & 4) != 0;
    int wid = (blockIdx.x * blockDim.x + threadIdx.x) >> 6;
    int nw = (gridDim.x * blockDim.x) >> 6;
    for (int v = wid; v < N; v += nw) {
        float a8[4];
        float a9 = 0.f;
        if (eslot == 0) {
            unpack_set2(*(const uint2*)(x8d + (size_t)v * 8 + fp * 4), a8);
            if (fp == 1) a9 = bf2f(x9d[v]);
        } else {
#pragma unroll
            for (int j = 0; j < 4; j++) a8[j] = 0.f;
        }
        int e = rowptr[v + 1];
        for (int i = rowptr[v] + eslot; i < e; i += 32) {
            int u = col[i];
            unpack_add2(*(const uint2*)(x8d + (size_t)u * 8 + fp * 4), a8);
            if (fp == 1) a9 += bf2f(x9d[u]);
        }
        // halving reduction of a8 over lane bits 1..5 (9 shfl)
        float s0 = a8[0] + __shfl_xor(a8[0], 2);
        float s1 = a8[1] + __shfl_xor(a8[1], 2);
        float s2 = a8[2] + __shfl_xor(a8[2], 2);
        float s3 = a8[3] + __shfl_xor(a8[3], 2);
        float k0 = bit1 ? s2 : s0;
        float k1 = bit1 ? s3 : s1;
        k0 += __shfl_xor(k0, 4);
        k1 += __shfl_xor(k1, 4);
        float c = bit2 ? k1 : k0;
        c += __shfl_xor(c, 8);
        c += __shfl_xor(c, 16);
        c += __shfl_xor(c, 32);
        // lane L holds A8[f], f = 4*(L&1) + 2*((L>>1)&1) + ((L>>2)&1)
        // full butterfly for a9 (6 shfl)
        a9 += __shfl_xor(a9, 1);
        a9 += __shfl_xor(a9, 2);
        a9 += __shfl_xor(a9, 4);
        a9 += __shfl_xor(a9, 8);
        a9 += __shfl_xor(a9, 16);
        a9 += __shfl_xor(a9, 32);
        // combine: accf = sum_k A8[k]*W1a[k][lane] + a9*w1b[lane]
        float accf = a9 * w1b;
#pragma unroll
        for (int k = 0; k < 8; k++) {
            int Lk = (k >> 2) | (((k >> 1) & 1) << 1) | ((k & 1) << 2);
            accf += __shfl(c, Lk) * w1a[k];
        }
        float h = fmaxf(dinv[v] * accf + bias, 0.f);
        h1[(size_t)v * HID + lane] = f2bf(h);
    }
}

// ---- gather core (64-feat rows): round-8 halving reduction ----
__device__ __forceinline__ float gather_node_one(const u16* __restrict__ y,
                                                 const int* __restrict__ rowptr,
                                                 const int* __restrict__ col,
                                                 float dv, float bias,
                                                 int v, int eslot, int fg) {
    float acc[8];
    const u16* yf = y + fg * 8;
    if (eslot == 0) {
        unpack_set(*(const uint4*)(yf + (size_t)v * HID), acc);
    } else {
#pragma unroll
        for (int j = 0; j < 8; j++) acc[j] = 0.f;
    }
    int e = rowptr[v + 1];
    for (int i = rowptr[v] + eslot; i < e; i += 8) {
        int u = col[i];
        uint4 r = *(const uint4*)(yf + (size_t)u * HID);
        unpack_add(r, acc);
    }
    bool e0 = (eslot & 1) != 0, e1 = (eslot & 2) != 0, e2 = (eslot & 4) != 0;
    float s[8];
#pragma unroll
    for (int j = 0; j < 8; j++) s[j] = acc[j] + __shfl_xor(acc[j], 8);
    float b4[4];
#pragma unroll
    for (int k = 0; k < 4; k++) b4[k] = e0 ? s[k + 4] : s[k];
#pragma unroll
    for (int k = 0; k < 4; k++) b4[k] += __shfl_xor(b4[k], 16);
    float c2[2];
    c2[0] = e1 ? b4[2] : b4[0];
    c2[1] = e1 ? b4[3] : b4[1];
    c2[0] += __shfl_xor(c2[0], 32);
    c2[1] += __shfl_xor(c2[1], 32);
    float val = e2 ? c2[1] : c2[0];
    return fmaxf(dv * val + bias, 0.f);
}

// ---- agg layer 2 ----
__global__ __launch_bounds__(256, 4) void k_agg(
        const u16* __restrict__ y, const int* __restrict__ rowptr,
        const int* __restrict__ col, const float* __restrict__ dinv,
        const u16* __restrict__ bseg, int N, u16* __restrict__ h) {
    int lane = threadIdx.x & 63;
    int eslot = lane >> 3, fg = lane & 7;
    int idx = fg * 8 + ((eslot & 1) << 2) + (eslot & 2) + ((eslot >> 2) & 1);
    float bias = bf2f(bseg[idx]);
    int wid = (blockIdx.x * blockDim.x + threadIdx.x) >> 6;
    int nw = (gridDim.x * blockDim.x) >> 6;
    for (int v = wid; v < N; v += nw) {
        float hv = gather_node_one(y, rowptr, col, dinv[v], bias, v, eslot, fg);
        h[(size_t)v * HID + idx] = f2bf(hv);
    }
}

// ---- agg layer 3 + fused pooling ----
__global__ __launch_bounds__(256, 4) void k_aggpool(
        const u16* __restrict__ y, const int* __restrict__ rowptr,
        const int* __restrict__ col, const float* __restrict__ dinv,
        const u16* __restrict__ bseg, const int* __restrict__ batch, int N,
        float* __restrict__ hsum, int* __restrict__ hmax, int* __restrict__ cnt) {
    int lane = threadIdx.x & 63;
    int eslot = lane >> 3, fg = lane & 7;
    int idx = fg * 8 + ((eslot & 1) << 2) + (eslot & 2) + ((eslot >> 2) & 1);
    float bias = bf2f(bseg[idx]);
    int wid = (blockIdx.x * blockDim.x + threadIdx.x) >> 6;
    int nw = (gridDim.x * blockDim.x) >> 6;
    int cpw = (N + nw - 1) / nw;
    int v0 = wid * cpw;
    int v1 = v0 + cpw; if (v1 > N) v1 = N;
    int gcur = -1, pcnt = 0;
    float psum = 0.f, pmax = 0.f;
    for (int v = v0; v < v1; ++v) {
        float hv = gather_node_one(y, rowptr, col, dinv[v], bias, v, eslot, fg);
        int g = batch[v];
        if (g != gcur) {
            if (gcur >= 0) {
                atomicAdd(&hsum[gcur * HID + idx], psum);
                atomicMax(&hmax[gcur * HID + idx], __float_as_int(pmax));
                if (lane == 0) atomicAdd(&cnt[gcur], pcnt);
            }
            psum = 0.f; pmax = 0.f; pcnt = 0;
            gcur = g;
        }
        pcnt++;
        psum += hv;
        pmax = fmaxf(pmax, hv);
    }
    if (gcur >= 0) {
        atomicAdd(&hsum[gcur * HID + idx], psum);
        atomicMax(&hmax[gcur * HID + idx], __float_as_int(pmax));
        if (lane == 0) atomicAdd(&cnt[gcur], pcnt);
    }
}

// ---- MFMA 64x64 dense: y = dinv * (h@W) ----
__global__ __launch_bounds__(256, 4) void k_mm(
        const u16* __restrict__ h, const u16* __restrict__ W,
        const float* __restrict__ dinv, int N, u16* __restrict__ y) {
    int lane = threadIdx.x & 63;
    int q = lane >> 4, m = lane & 15;
    int wid = (blockIdx.x * blockDim.x + threadIdx.x) >> 6;
    int nw = (gridDim.x * blockDim.x) >> 6;
    short8 bfrag[4][2];
#pragma unroll
    for (int t = 0; t < 4; ++t)
#pragma unroll
        for (int kh = 0; kh < 2; ++kh) {
            short8 bv;
#pragma unroll
            for (int j = 0; j < 8; ++j)
                bv[j] = (short)W[(kh * 32 + q * 8 + j) * HID + t * 16 + m];
            bfrag[t][kh] = bv;
        }
    const float4v zero = {0.f, 0.f, 0.f, 0.f};
    int ntiles = (N + 15) >> 4;
    for (int tile = wid; tile < ntiles; tile += nw) {
        int base = tile * 16;
        int row = base + m;
        short8 a0 = {0, 0, 0, 0, 0, 0, 0, 0}, a1 = a0;
        if (row < N) {
            uint4 r0 = *(const uint4*)(h + (size_t)row * HID + q * 8);
            uint4 r1 = *(const uint4*)(h + (size_t)row * HID + 32 + q * 8);
            a0 = __builtin_bit_cast(short8, r0);
            a1 = __builtin_bit_cast(short8, r1);
        }
        float4v c[4];
#pragma unroll
        for (int t = 0; t < 4; ++t) c[t] = zero;
#pragma unroll
        for (int t = 0; t < 4; ++t) {
            c[t] = __builtin_amdgcn_mfma_f32_16x16x32_bf16(a0, bfrag[t][0], c[t], 0, 0, 0);
            c[t] = __builtin_amdgcn_mfma_f32_16x16x32_bf16(a1, bfrag[t][1], c[t], 0, 0, 0);
        }
#pragma unroll
        for (int r = 0; r < 4; ++r) {
            int node = base + q * 4 + r;
            if (node < N) {
                float dv = dinv[node];
#pragma unroll
                for (int t = 0; t < 4; ++t)
                    y[(size_t)node * HID + t * 16 + m] = f2bf(c[t][r] * dv);
            }
        }
    }
}

// ---- final linear ----
__global__ void k_final(const float* __restrict__ hsum, const int* __restrict__ hmaxi,
                        const int* __restrict__ cnt, const u16* __restrict__ wlseg,
                        const u16* __restrict__ blseg, const int* __restrict__ flag,
                        int G, void* __restrict__ out) {
    __shared__ float w[2 * HID * HID];
    int tid = threadIdx.x;
    for (int i = tid; i < 2 * HID * HID; i += blockDim.x) w[i] = bf2f(wlseg[i]);
    __syncthreads();
    int g = blockIdx.x * 4 + (tid >> 6);
    int f = tid & 63;
    if (g >= G) return;
    float inv = 1.f / fmaxf((float)cnt[g], 1.f);
    float acc = bf2f(blseg[f]);
#pragma unroll 8
    for (int k = 0; k < HID; k++) acc += (hsum[g * HID + k] * inv) * w[k * HID + f];
#pragma unroll 8
    for (int k = 0; k < HID; k++) acc += __int_as_float(hmaxi[g * HID + k]) * w[(HID + k) * HID + f];
    int mode = *flag;
    if (mode) ((float*)out)[g * HID + f] = acc;
    else      ((u16*)out)[g * HID + f] = f2bf(acc);
}

extern "C" void kernel_launch(void* const* d_in, const int* in_sizes, int n_in,
                              void* d_out, int out_size, void* d_ws, size_t ws_size,
                              hipStream_t stream) {
    const void* x  = d_in[0];
    const int*  ei = (const int*)d_in[1];
    const int*  batch = (const int*)d_in[3];

    const int NX = in_sizes[0];
    const int N  = NX / MOLD;
    const int E  = in_sizes[1] / 2;
    const int G  = out_size / HID;
    const int nb = (N + (1 << BSH) - 1) >> BSH;

    char* p = (char*)d_ws;
    auto alloc = [&](size_t bytes) -> char* {
        char* r = p;
        p += (bytes + 255) & ~(size_t)255;
        return r;
    };
    int*   flag    = (int*)alloc(256);
    int*   rowptr  = (int*)alloc((size_t)(N + 1) * 4);
    float* dinv    = (float*)alloc((size_t)N * 4);
    int*   cntmat  = (int*)alloc((size_t)nb * NBLK * 4);
    u16*   wbf     = (u16*)alloc((size_t)17216 * 2);
    int*   colb    = (int*)alloc((size_t)E * 4);
    // hbuf region reused sequentially: staging (CSR) -> {x8d,x9d} -> y2 -> y3
    size_t hb = (size_t)N * HID * 2;           // 25.6 MB
    size_t sb = (size_t)E * 4;                 // 12.8 MB
    size_t xs = (size_t)N * 9 * 2;             // 3.6 MB (x8 3.2 + x9 0.4)
    size_t ub = hb; if (sb > ub) ub = sb; if (xs > ub) ub = xs;
    char* hbuf = alloc(ub);
    unsigned* staging = (unsigned*)hbuf;
    u16*      x8d     = (u16*)hbuf;                       // N*8 u16
    u16*      x9d     = (u16*)(hbuf + (size_t)N * 8 * 2); // N u16
    u16*      hbf     = (u16*)hbuf;
    u16*   ybf  = (u16*)alloc((size_t)N * HID * 2);
    float* hsum = (float*)alloc((size_t)G * HID * 4);
    int*   hmax = (int*)alloc((size_t)G * HID * 4);
    int*   cnt  = (int*)alloc((size_t)G * 4);

    k_detect<<<1, 256, 0, stream>>>((const u16*)x, 8192, flag);
    k_cvt_w<<<68, 256, 0, stream>>>(d_in[4], d_in[5], d_in[6], d_in[7],
                                    d_in[8], d_in[9], d_in[10], d_in[11], flag, wbf,
                                    hsum, hmax, cnt, G);

    int chunk = (E + NBLK - 1) / NBLK;
    k_hist<<<NBLK, 256, 0, stream>>>(ei, E, nb, chunk, cntmat);
    k_scanmat<<<1, 1024, 0, stream>>>(cntmat, nb * NBLK);
    k_scatter<<<NBLK, 256, 0, stream>>>(ei, E, nb, chunk, cntmat, staging);
    k_p4<<<nb, 256, 0, stream>>>(staging, cntmat, nb, N, E, colb, rowptr, dinv);

    // stage x8/x9 (L2-resident tables) over dead staging; layer-1 gather + W1
    k_cvt_x<<<(N * 9 + 255) / 256, 256, 0, stream>>>(x, dinv, flag, N, x8d, x9d);
    k_aggx<<<2048, 256, 0, stream>>>(x8d, x9d, rowptr, colb, dinv, wbf + 0, wbf + 576,
                                     N, ybf);                                        // h1
    k_mm<<<1024, 256, 0, stream>>>(ybf, wbf + 640, dinv, N, hbf);                    // y2
    k_agg<<<2048, 256, 0, stream>>>(hbf, rowptr, colb, dinv, wbf + 4736, N, ybf);    // h2
    k_mm<<<1024, 256, 0, stream>>>(ybf, wbf + 4800, dinv, N, hbf);                   // y3
    k_aggpool<<<2048, 256, 0, stream>>>(hbf, rowptr, colb, dinv, wbf + 8896, batch, N,
                                        hsum, hmax, cnt);

    k_final<<<(G + 3) / 4, 256, 0, stream>>>(hsum, hmax, cnt, wbf + 8960, wbf + 17152,
                                             flag, G, d_out);
}